// Round 19
// baseline (57.218 us; speedup 1.0000x reference)
//
#include <hip/hip_runtime.h>
#include <hip/hip_bf16.h>

// out[b,v] = dot(OT[b, pid[v], :], W[v, :]) + bias[v]
// B=32, Q=180, H=768, V=19004. fp32 in/out, bf16 MFMA inside.
#define BB 32
#define QQ 180
#define HH 768
#define VV 19004
#define KH 384       // K per half
#define BKT 256      // padded bucket capacity per q (4 slots x 64)
#define SLOTS 4
#define SB2 (QQ * BKT)   // 46080: res/sorted stride in padded pos space
#define STRIDE 392   // OT LDS row stride in bf16 elems (384 + 8 pad)

// ws layout (bytes)
#define WS_CNT    0        // QQ ints
#define WS_SORTED 1024     // SB2 ints = 184320
#define WS_POSOF  186368   // VV ints = 76016
#define WS_RES    263168   // 2 * 32 * 46080 * 4 = 11,796,480

typedef __attribute__((ext_vector_type(8))) short short8v;  // 8 bf16 (4 VGPR)
typedef __attribute__((ext_vector_type(4))) float f32x4;

__device__ __forceinline__ unsigned pk2(float lo, float hi) {  // 2xbf16 RNE, packed
    __hip_bfloat162 r = __float22bfloat162_rn(make_float2(lo, hi));
    unsigned u;
    __builtin_memcpy(&u, &r, 4);
    return u;
}

// ---------- prep (ONE dispatch): per-q bucket build, atomic-free ----------
// Block q scans all pid (L2-broadcast, 19 coalesced iters @1024 thr); ranks
// its matches via ballot+popc + 16-wave LDS scan; writes sorted/posOf into
// padded slot q*256+rank. No atomics, no cross-block dependency, no desc.
__global__ void prep_k(const int* __restrict__ pid, int* __restrict__ sorted,
                       int* __restrict__ posOf, int* __restrict__ cnt) {
    __shared__ int wsum[16];
    const int q = blockIdx.x;
    const int t = threadIdx.x;          // 1024 threads = 16 waves
    const int lane = t & 63;
    const int wid = t >> 6;
    int run = 0;                        // block-uniform running count
    for (int base = 0; base < VV; base += 1024) {
        const int v = base + t;
        const bool m = (v < VV) && (pid[v] == q);
        const unsigned long long mask = __ballot(m);
        const int wpre = __popcll(mask & ((1ull << lane) - 1ull));
        if (lane == 0) wsum[wid] = __popcll(mask);
        __syncthreads();
        int wb = 0, tot = 0;
#pragma unroll
        for (int j = 0; j < 16; ++j) {   // broadcast LDS reads (conflict-free)
            const int s = wsum[j];
            wb += (j < wid) ? s : 0;
            tot += s;
        }
        if (m) {
            const int pos = q * BKT + run + wb + wpre;
            sorted[pos] = v;
            posOf[v] = pos;
        }
        run += tot;
        __syncthreads();
    }
    if (t == 0) cnt[q] = run;           // run <= 256 (mu=105.6, sigma=10.3)
}

// ---------- main: MFMA 16x16x32 bf16 — R16 inner loop, static grid ----------
// grid = 180*4*2: q = bid>>3, slot = (bid>>1)&3, kh = bid&1. Empty slots exit
// early. 4 waves; wave w owns v-tile w (16 v's), both b-tiles, K=384 (12
// steps x2 MFMA). OT half staged once in LDS as bf16 (packed cvt); W burst:
// 24 outstanding float4/lane before the barrier. Full-line padded-pos stores.
__launch_bounds__(256)
__global__ void main_k(const float* __restrict__ OT, const float* __restrict__ W,
                       const int* __restrict__ sorted, const int* __restrict__ cnt,
                       float* __restrict__ res) {
    const int bid = blockIdx.x;
    const int q    = bid >> 3;
    const int slot = (bid >> 1) & 3;
    const int kh   = bid & 1;
    const int len  = __builtin_amdgcn_readfirstlane(
                         min(64, cnt[q] - slot * 64));
    if (len <= 0) return;               // block-uniform
    const int start = q * BKT + slot * 64;   // padded pos space
    const int tid = threadIdx.x;

    __shared__ short OTlds[BB * STRIDE];  // 25,088 B

    // stage OT[0..31][q][kh*384 .. +384) as bf16 (coalesced fp32 reads)
    {
        const int r = tid >> 3;   // b row 0..31
        const int o = tid & 7;    // octet
        const float* src = OT + ((size_t)r * QQ + q) * HH + kh * KH + o * 8;
        short* dst = &OTlds[r * STRIDE + o * 8];
#pragma unroll
        for (int it = 0; it < 6; ++it) {
            const float4 f0 = *(const float4*)(src + it * 64);
            const float4 f1 = *(const float4*)(src + it * 64 + 4);
            int4 p;
            p.x = (int)pk2(f0.x, f0.y); p.y = (int)pk2(f0.z, f0.w);
            p.z = (int)pk2(f1.x, f1.y); p.w = (int)pk2(f1.z, f1.w);
            *(int4*)(dst + it * 64) = p;
        }
    }

    const int lane = tid & 63;
    const int w = tid >> 6;           // v-tile
    const int co = lane & 15;         // frag col
    const int kq = lane >> 4;         // k-quad
    const int vl = 16 * w + co;       // v-local in slot
    const int vg = sorted[start + min(vl, len - 1)];
    const float4* wp4 = (const float4*)(W + (size_t)vg * HH + kh * KH + kq * 8);
    const short* a0 = &OTlds[co * STRIDE + kq * 8];

    // burst: issue ALL W loads before any use (24 outstanding 16B/lane)
    float4 wf[24];
#pragma unroll
    for (int kk = 0; kk < 12; ++kk) {
        wf[2 * kk]     = wp4[kk * 8];
        wf[2 * kk + 1] = wp4[kk * 8 + 1];
    }

    __syncthreads();

    f32x4 acc0 = {0.f, 0.f, 0.f, 0.f};
    f32x4 acc1 = {0.f, 0.f, 0.f, 0.f};
#pragma unroll
    for (int kk = 0; kk < 12; ++kk) {
        const float4 wf0 = wf[2 * kk];
        const float4 wf1 = wf[2 * kk + 1];
        int4 p;
        p.x = (int)pk2(wf0.x, wf0.y); p.y = (int)pk2(wf0.z, wf0.w);
        p.z = (int)pk2(wf1.x, wf1.y); p.w = (int)pk2(wf1.z, wf1.w);
        short8v bf;
        __builtin_memcpy(&bf, &p, 16);
        const short8v a0v = *(const short8v*)(a0 + kk * 32);
        const short8v a1v = *(const short8v*)(a0 + 16 * STRIDE + kk * 32);
        acc0 = __builtin_amdgcn_mfma_f32_16x16x32_bf16(a0v, bf, acc0, 0, 0, 0);
        acc1 = __builtin_amdgcn_mfma_f32_16x16x32_bf16(a1v, bf, acc1, 0, 0, 0);
    }

    // C[row=b][col=v]: row = (lane>>4)*4 + reg, col = lane&15  (m89-verified)
    if (vl < len) {
        float* rp = res + (size_t)(kh * BB) * SB2 + start + vl;
#pragma unroll
        for (int r2 = 0; r2 < 4; ++r2) {
            rp[(size_t)(kq * 4 + r2) * SB2]      = acc0[r2];
            rp[(size_t)(16 + kq * 4 + r2) * SB2] = acc1[r2];
        }
    }
}

// ---------- combine: gather res via posOf (L2), coalesced out writes ----------
__global__ void combine_k(const float* __restrict__ res, const int* __restrict__ posOf,
                          const float* __restrict__ bias, float* __restrict__ out) {
    const int v = blockIdx.x * 256 + threadIdx.x;
    if (v >= VV) return;
    const int b = blockIdx.y;
    const int pos = posOf[v];
    const float s = res[(size_t)b * SB2 + pos] + res[(size_t)(BB + b) * SB2 + pos];
    out[(size_t)b * VV + v] = s + bias[v];
}

extern "C" void kernel_launch(void* const* d_in, const int* in_sizes, int n_in,
                              void* d_out, int out_size, void* d_ws, size_t ws_size,
                              hipStream_t stream) {
    const float* OT   = (const float*)d_in[0];  // [B,Q,H]
    const float* W    = (const float*)d_in[1];  // [V,H]
    const float* bias = (const float*)d_in[2];  // [V]
    const int*   pid  = (const int*)d_in[3];    // [V]
    float* out = (float*)d_out;                 // [B,V]

    char* ws = (char*)d_ws;
    int*   cnt    = (int*)(ws + WS_CNT);
    int*   sorted = (int*)(ws + WS_SORTED);
    int*   posOf  = (int*)(ws + WS_POSOF);
    float* res    = (float*)(ws + WS_RES);

    prep_k<<<QQ, 1024, 0, stream>>>(pid, sorted, posOf, cnt);

    main_k<<<QQ * SLOTS * 2, 256, 0, stream>>>(OT, W, sorted, cnt, res);

    combine_k<<<dim3((VV + 255) / 256, BB), 256, 0, stream>>>(res, posOf, bias, out);
}

// Round 20
// 40.846 us; speedup vs baseline: 1.4008x; 1.4008x over previous
//
#include <hip/hip_runtime.h>
#include <hip/hip_bf16.h>

// out[b,v] = dot(OT[b, pid[v], :], W[v, :]) + bias[v]
// B=32, Q=180, H=768, V=19004. fp32 in/out, bf16 MFMA inside.
#define BB 32
#define QQ 180
#define HH 768
#define VV 19004
#define VB 64
#define SB 19008     // res stride (pos dim)
#define MAXDESC 480
#define ST 776       // OT LDS row stride in bf16 elems (768 + 8 pad)
#define NB 80        // prep blocks
#define CH 238       // v's per prep block (80*238 = 19040 >= VV)

// ws layout (bytes)
#define WS_H      0        // NB*QQ ints = 57600
#define WS_NTOT   65536    // 1 int
#define WS_DESC   66560    // MAXDESC int4 = 7680
#define WS_SORTED 74752    // VV ints = 76016
#define WS_POSOF  151552   // VV ints = 76016
#define WS_RES    229376   // 32 * 19008 * 4 = 2,433,024

typedef __attribute__((ext_vector_type(8))) short short8v;  // 8 bf16 (4 VGPR)
typedef __attribute__((ext_vector_type(4))) float f32x4;

__device__ __forceinline__ unsigned pk2(float lo, float hi) {  // 2xbf16 RNE, packed
    __hip_bfloat162 r = __float22bfloat162_rn(make_float2(lo, hi));
    unsigned u;
    __builtin_memcpy(&u, &r, 4);
    return u;
}

// ---------- prep 1: per-block LDS histograms (R16 verbatim) ----------
__global__ void hist_k(const int* __restrict__ pid, int* __restrict__ h) {
    __shared__ int lc[QQ];
    const int t = threadIdx.x, b = blockIdx.x;
    if (t < QQ) lc[t] = 0;
    __syncthreads();
    const int v = b * CH + t;
    if (t < CH && v < VV) atomicAdd(&lc[pid[v]], 1);
    __syncthreads();
    if (t < QQ) h[b * QQ + t] = lc[t];
}

// ---------- prep 2: local scan + scatter; block 0 emits desc/ntot (R16) ------
__global__ void scat_k(const int* __restrict__ pid, const int* __restrict__ h,
                       int* __restrict__ sorted, int* __restrict__ posOf,
                       int4* __restrict__ desc, int* __restrict__ ntot) {
    __shared__ int s1[256];
    __shared__ int s2[256];
    __shared__ int cur[QQ];
    const int t = threadIdx.x, b = blockIdx.x;
    int c = 0, mybase = 0;
    if (t < QQ) {
        for (int i = 0; i < NB; ++i) {       // column sum + prefix before b
            if (i == b) mybase = c;
            c += h[i * QQ + t];
        }
    }
    s1[t] = c;
    __syncthreads();
    for (int off = 1; off < 256; off <<= 1) {
        int a = (t >= off) ? s1[t - off] : 0;
        __syncthreads();
        s1[t] += a;
        __syncthreads();
    }
    const int qs = s1[t] - c;                // exclusive prefix over q
    if (t < QQ) cur[t] = qs + mybase;
    if (b == 0) {                            // desc + ntot (uniform branch)
        const int nch = (c + VB - 1) / VB;
        s2[t] = nch;
        __syncthreads();
        for (int off = 1; off < 256; off <<= 1) {
            int a = (t >= off) ? s2[t - off] : 0;
            __syncthreads();
            s2[t] += a;
            __syncthreads();
        }
        if (t < QQ) {
            const int cb = s2[t] - nch;
            for (int j = 0; j < nch; ++j)
                desc[cb + j] = make_int4(t, qs + j * VB, min(VB, c - j * VB), 0);
        }
        if (t == 255) *ntot = s2[255];
    }
    __syncthreads();
    const int v = b * CH + t;
    if (t < CH && v < VV) {
        const int q = pid[v];
        const int pos = atomicAdd(&cur[q], 1);   // LDS cursors, 1 block
        sorted[pos] = v;
        posOf[v] = pos;
    }
}

// ---------- main: MFMA 16x16x32 bf16, block = chunk, FULL K=768 ----------
// 374 active blocks. OT[32][768] staged once as bf16 (48.5 KB LDS). W: 48
// float4/lane in a rolling window — A(24) pre-barrier, B0(12)/B1(12) injected
// between 6-step compute groups so loads stay continuously in flight.
// Single res plane (no K-split), full-line pos-space stores.
#define MSTEP(kk, F0, F1)                                                     \
    {                                                                         \
        int4 p_;                                                              \
        p_.x = (int)pk2((F0).x, (F0).y); p_.y = (int)pk2((F0).z, (F0).w);     \
        p_.z = (int)pk2((F1).x, (F1).y); p_.w = (int)pk2((F1).z, (F1).w);     \
        short8v bf_;                                                          \
        __builtin_memcpy(&bf_, &p_, 16);                                      \
        const short8v a0v_ = *(const short8v*)(a0p + (kk) * 32);              \
        const short8v a1v_ = *(const short8v*)(a0p + 16 * ST + (kk) * 32);    \
        acc0 = __builtin_amdgcn_mfma_f32_16x16x32_bf16(a0v_, bf_, acc0, 0, 0, 0); \
        acc1 = __builtin_amdgcn_mfma_f32_16x16x32_bf16(a1v_, bf_, acc1, 0, 0, 0); \
    }

__launch_bounds__(256)
__global__ void main_k(const float* __restrict__ OT, const float* __restrict__ W,
                       const int* __restrict__ sorted, const int4* __restrict__ desc,
                       const int* __restrict__ ntot, float* __restrict__ res) {
    const int nt = *ntot;
    const int ci = blockIdx.x;
    if (ci >= nt) return;
    const int4 d = desc[ci];
    const int q     = __builtin_amdgcn_readfirstlane(d.x);
    const int start = __builtin_amdgcn_readfirstlane(d.y);
    const int len   = __builtin_amdgcn_readfirstlane(d.z);
    const int tid = threadIdx.x;

    __shared__ short OTlds[BB * ST];  // 49,664 B

    // stage OT[0..31][q][0..768) as bf16 (coalesced fp32 reads, packed cvt)
    {
        const int r = tid >> 3;   // b row 0..31
        const int o = tid & 7;    // octet
        const float* src = OT + ((size_t)r * QQ + q) * HH + o * 8;
        short* dst = &OTlds[r * ST + o * 8];
#pragma unroll
        for (int it = 0; it < 12; ++it) {
            const float4 f0 = *(const float4*)(src + it * 64);
            const float4 f1 = *(const float4*)(src + it * 64 + 4);
            int4 p;
            p.x = (int)pk2(f0.x, f0.y); p.y = (int)pk2(f0.z, f0.w);
            p.z = (int)pk2(f1.x, f1.y); p.w = (int)pk2(f1.z, f1.w);
            *(int4*)(dst + it * 64) = p;
        }
    }

    const int lane = tid & 63;
    const int w = tid >> 6;           // v-tile
    const int co = lane & 15;         // frag col
    const int kq = lane >> 4;         // k-quad
    const int vl = 16 * w + co;       // v-local in chunk
    const int vg = sorted[start + min(vl, len - 1)];
    const float4* wp4 = (const float4*)(W + (size_t)vg * HH + kq * 8);
    const short* a0p = &OTlds[co * ST + kq * 8];

    // burst A: K-steps 0..11 (24 outstanding 16B loads/lane)
    float4 wa[24];
#pragma unroll
    for (int kk = 0; kk < 12; ++kk) {
        wa[2 * kk]     = wp4[kk * 8];
        wa[2 * kk + 1] = wp4[kk * 8 + 1];
    }

    __syncthreads();

    f32x4 acc0 = {0.f, 0.f, 0.f, 0.f};
    f32x4 acc1 = {0.f, 0.f, 0.f, 0.f};
    float4 wb0[12], wb1[12];

    // compute steps 0..5 (consume wa[0..11])
#pragma unroll
    for (int kk = 0; kk < 6; ++kk) MSTEP(kk, wa[2 * kk], wa[2 * kk + 1]);
    // issue B0: steps 12..17
#pragma unroll
    for (int j = 0; j < 6; ++j) {
        wb0[2 * j]     = wp4[(12 + j) * 8];
        wb0[2 * j + 1] = wp4[(12 + j) * 8 + 1];
    }
    // compute steps 6..11 (consume wa[12..23])
#pragma unroll
    for (int kk = 6; kk < 12; ++kk) MSTEP(kk, wa[2 * kk], wa[2 * kk + 1]);
    // issue B1: steps 18..23
#pragma unroll
    for (int j = 0; j < 6; ++j) {
        wb1[2 * j]     = wp4[(18 + j) * 8];
        wb1[2 * j + 1] = wp4[(18 + j) * 8 + 1];
    }
    // compute steps 12..17
#pragma unroll
    for (int kk = 12; kk < 18; ++kk)
        MSTEP(kk, wb0[2 * (kk - 12)], wb0[2 * (kk - 12) + 1]);
    // compute steps 18..23
#pragma unroll
    for (int kk = 18; kk < 24; ++kk)
        MSTEP(kk, wb1[2 * (kk - 18)], wb1[2 * (kk - 18) + 1]);

    // C[row=b][col=v]: row = (lane>>4)*4 + reg, col = lane&15  (m89-verified)
    if (vl < len) {
        float* rp = res + start + vl;
#pragma unroll
        for (int r2 = 0; r2 < 4; ++r2) {
            rp[(size_t)(kq * 4 + r2) * SB]      = acc0[r2];
            rp[(size_t)(16 + kq * 4 + r2) * SB] = acc1[r2];
        }
    }
}

// ---------- combine: gather 1 res plane via posOf, coalesced out writes ------
__global__ void combine_k(const float* __restrict__ res, const int* __restrict__ posOf,
                          const float* __restrict__ bias, float* __restrict__ out) {
    const int v = blockIdx.x * 256 + threadIdx.x;
    if (v >= VV) return;
    const int b = blockIdx.y;
    const int pos = posOf[v];
    out[(size_t)b * VV + v] = res[(size_t)b * SB + pos] + bias[v];
}

extern "C" void kernel_launch(void* const* d_in, const int* in_sizes, int n_in,
                              void* d_out, int out_size, void* d_ws, size_t ws_size,
                              hipStream_t stream) {
    const float* OT   = (const float*)d_in[0];  // [B,Q,H]
    const float* W    = (const float*)d_in[1];  // [V,H]
    const float* bias = (const float*)d_in[2];  // [V]
    const int*   pid  = (const int*)d_in[3];    // [V]
    float* out = (float*)d_out;                 // [B,V]

    char* ws = (char*)d_ws;
    int*   h      = (int*)(ws + WS_H);
    int*   ntot   = (int*)(ws + WS_NTOT);
    int4*  desc   = (int4*)(ws + WS_DESC);
    int*   sorted = (int*)(ws + WS_SORTED);
    int*   posOf  = (int*)(ws + WS_POSOF);
    float* res    = (float*)(ws + WS_RES);

    hist_k<<<NB, 256, 0, stream>>>(pid, h);
    scat_k<<<NB, 256, 0, stream>>>(pid, h, sorted, posOf, desc, ntot);

    main_k<<<MAXDESC, 256, 0, stream>>>(OT, W, sorted, desc, ntot, res);

    combine_k<<<dim3((VV + 255) / 256, BB), 256, 0, stream>>>(res, posOf, bias, out);
}